// Round 10
// baseline (25.056 us; speedup 1.0000x reference)
//
#include <hip/hip_runtime.h>
#include <math.h>

#define BB 256
#define NN 50
#define DD 128
#define MAXA 2000
#define NEGV -9e15f
#define NATTR 512                      // 16 m-groups x 32 k-splits

// u16 strides; 16B-granule strides are ODD (17/9/5) -> bank-quads balanced, NO XOR
#define H_S   136                      // H  [64 i][128 d + pad]
#define HT_S  72                       // HT [128 d][64 i + pad]
#define AL_S  72                       // alpha [64 i][64 j + pad]

#define H_OFF   0
#define HT_OFF  (64 * H_S)             // 8704
#define AL_OFF  (HT_OFF + 128 * HT_S)  // 17920
#define ADJ_OFF (AL_OFF + 64 * AL_S)   // 22528
#define LDS_US  (ADJ_OFF + 64 * 64)    // 26624 u16 = 53248 B

typedef __attribute__((ext_vector_type(8))) short        s8b;
typedef __attribute__((ext_vector_type(4))) float        f32x4;
typedef __attribute__((ext_vector_type(4))) unsigned int u32x4;

static __device__ __forceinline__ unsigned short f2bf(float x) {
    unsigned int u = __float_as_uint(x);
    u = u + 0x7fffu + ((u >> 16) & 1u);          // RNE
    return (unsigned short)(u >> 16);
}
static __device__ __forceinline__ float bf2f(unsigned int s) {
    return __uint_as_float(s << 16);
}
static __device__ __forceinline__ unsigned int pack2(float lo, float hi) {
    return (unsigned)f2bf(lo) | ((unsigned)f2bf(hi) << 16);
}
static __device__ __forceinline__ f32x4 mfma16(u32x4 a, u32x4 b, f32x4 c) {
    return __builtin_amdgcn_mfma_f32_16x16x32_bf16(
        __builtin_bit_cast(s8b, a), __builtin_bit_cast(s8b, b), c, 0, 0, 0);
}

__global__ __launch_bounds__(256) void sg_fused_kernel(
    const int* __restrict__ inputs,      // [B,N]
    const int* __restrict__ adj,         // [B,N,N]
    const float* __restrict__ A_attr,    // [B,MAXA]
    const float* __restrict__ embedding, // [N_NODE,D]
    const float* __restrict__ attr_emb,  // [MAXA,D]
    const float* __restrict__ a0,
    const float* __restrict__ a1,
    const float* __restrict__ a2,
    const float* __restrict__ a3,
    float* __restrict__ out,             // [B,N,D]
    float* __restrict__ ws)              // [512][16][128] f32 attr partials
{
    __shared__ __align__(16) unsigned short sh[LDS_US];
    const int blk  = blockIdx.x;
    const int tid  = threadIdx.x;
    const int w    = tid >> 6;
    const int lane = tid & 63;
    const int g    = lane >> 4;
    const int c    = lane & 15;
    const int goff = g * 8;

    if (blk >= NATTR) {
        // ================= GAT: one block per batch, wave w = i-tile w =================
        const int b = blk - NATTR;

        // ---- issue embedding gathers EARLY (latency hides under adj staging) ----
        const int  i_   = lane;
        const bool live = (i_ < NN);
        int node = 0;
        if (live) node = inputs[b * NN + i_];
        float4 gv[8];
        #pragma unroll
        for (int n = 0; n < 8; ++n) {
            gv[n] = make_float4(0.f, 0.f, 0.f, 0.f);
            if (live) gv[n] = *(const float4*)(embedding + (size_t)node * DD + (w * 8 + n) * 4);
        }
        // ---- adj -> LDS (zero-padded to 64x64) ----
        for (int idx = tid; idx < 4096; idx += 256) {
            const int i = idx >> 6, j = idx & 63;
            int a = 0;
            if (i < NN && j < NN) a = adj[(size_t)b * (NN * NN) + i * NN + j];
            sh[ADJ_OFF + idx] = (unsigned short)a;
        }
        // ---- convert + store H (row-major) and HT (transposed) ----
        #pragma unroll
        for (int n = 0; n < 8; ++n) {
            const int d4 = w * 8 + n;
            const unsigned short b0 = f2bf(gv[n].x), b1 = f2bf(gv[n].y);
            const unsigned short b2 = f2bf(gv[n].z), b3 = f2bf(gv[n].w);
            *(uint2*)(sh + H_OFF + i_ * H_S + d4 * 4) =
                make_uint2((unsigned)b0 | ((unsigned)b1 << 16),
                           (unsigned)b2 | ((unsigned)b3 << 16));
            sh[HT_OFF + (d4 * 4 + 0) * HT_S + i_] = b0;
            sh[HT_OFF + (d4 * 4 + 1) * HT_S + i_] = b1;
            sh[HT_OFF + (d4 * 4 + 2) * HT_S + i_] = b2;
            sh[HT_OFF + (d4 * 4 + 3) * HT_S + i_] = b3;
        }
        __syncthreads();

        // ---- hoist this wave's A-side row fragments, unpacked f32 + abs ----
        u32x4 hA[4];
        float hf[4][8], hb[4][8];
        #pragma unroll
        for (int dt = 0; dt < 4; ++dt) {
            hA[dt] = *(const u32x4*)(const void*)(sh + H_OFF + (w * 16 + c) * H_S + dt * 32 + goff);
            #pragma unroll
            for (int p = 0; p < 4; ++p) {
                const unsigned int hp = hA[dt][p];
                hf[dt][2 * p]     = bf2f(hp & 0xffffu);
                hf[dt][2 * p + 1] = bf2f(hp >> 16);
                hb[dt][2 * p]     = fabsf(hf[dt][2 * p]);
                hb[dt][2 * p + 1] = fabsf(hf[dt][2 * p + 1]);
            }
        }
        // ---- scores: e_k = (H⊙0.6a_k)·H^T + (|H|⊙0.4a_k)·|H|^T ----
        f32x4 accS[4][4];                 // [jt][k]
        #pragma unroll
        for (int jt = 0; jt < 4; ++jt)
            #pragma unroll
            for (int k = 0; k < 4; ++k) accS[jt][k] = (f32x4){0.f, 0.f, 0.f, 0.f};

        #pragma unroll
        for (int pass = 0; pass < 2; ++pass) {
            u32x4 Uf[4][2], Vf[4][2];
            #pragma unroll
            for (int kk = 0; kk < 2; ++kk) {
                const int k = pass * 2 + kk;
                const float* ap = (k == 0) ? a0 : (k == 1) ? a1 : (k == 2) ? a2 : a3;
                #pragma unroll
                for (int dt = 0; dt < 4; ++dt) {
                    const float4 aL = *(const float4*)(ap + dt * 32 + goff);
                    const float4 aH = *(const float4*)(ap + dt * 32 + goff + 4);
                    const float a8[8] = {aL.x, aL.y, aL.z, aL.w, aH.x, aH.y, aH.z, aH.w};
                    u32x4 U, V;
                    #pragma unroll
                    for (int p = 0; p < 4; ++p) {
                        U[p] = pack2(0.6f * a8[2 * p] * hf[dt][2 * p],
                                     0.6f * a8[2 * p + 1] * hf[dt][2 * p + 1]);
                        V[p] = pack2(0.4f * a8[2 * p] * hb[dt][2 * p],
                                     0.4f * a8[2 * p + 1] * hb[dt][2 * p + 1]);
                    }
                    Uf[dt][kk] = U; Vf[dt][kk] = V;
                }
            }
            #pragma unroll
            for (int jt = 0; jt < 4; ++jt) {
                #pragma unroll
                for (int dt = 0; dt < 4; ++dt) {
                    const u32x4 hB = *(const u32x4*)(const void*)(sh + H_OFF + (jt * 16 + c) * H_S + dt * 32 + goff);
                    u32x4 hBa;
                    #pragma unroll
                    for (int p = 0; p < 4; ++p) hBa[p] = hB[p] & 0x7fff7fffu;
                    accS[jt][pass * 2 + 0] = mfma16(Uf[dt][0], hB,  accS[jt][pass * 2 + 0]);
                    accS[jt][pass * 2 + 0] = mfma16(Vf[dt][0], hBa, accS[jt][pass * 2 + 0]);
                    accS[jt][pass * 2 + 1] = mfma16(Uf[dt][1], hB,  accS[jt][pass * 2 + 1]);
                    accS[jt][pass * 2 + 1] = mfma16(Vf[dt][1], hBa, accS[jt][pass * 2 + 1]);
                }
            }
        }

        // ---- adj select + in-register softmax (C/D: col=c, row=g*4+reg) ----
        float s_[4][4];
        #pragma unroll
        for (int jt = 0; jt < 4; ++jt) {
            #pragma unroll
            for (int reg = 0; reg < 4; ++reg) {
                const int il = w * 16 + g * 4 + reg;
                const int j  = jt * 16 + c;
                const int a  = (int)sh[ADJ_OFF + il * 64 + j];
                float sv = (a == 1) ? accS[jt][0][reg] : (a == 2) ? accS[jt][1][reg]
                         : (a == 3) ? accS[jt][2][reg] : (a == 4) ? accS[jt][3][reg] : NEGV;
                if (j >= NN) sv = -INFINITY;
                s_[jt][reg] = sv;
            }
        }
        #pragma unroll
        for (int reg = 0; reg < 4; ++reg) {
            float m = fmaxf(fmaxf(s_[0][reg], s_[1][reg]), fmaxf(s_[2][reg], s_[3][reg]));
            m = fmaxf(m, __shfl_xor(m, 1));
            m = fmaxf(m, __shfl_xor(m, 2));
            m = fmaxf(m, __shfl_xor(m, 4));
            m = fmaxf(m, __shfl_xor(m, 8));
            const float p0 = __expf(s_[0][reg] - m);
            const float p1 = __expf(s_[1][reg] - m);
            const float p2 = __expf(s_[2][reg] - m);
            const float p3 = __expf(s_[3][reg] - m);
            float sum = (p0 + p1) + (p2 + p3);
            sum += __shfl_xor(sum, 1);
            sum += __shfl_xor(sum, 2);
            sum += __shfl_xor(sum, 4);
            sum += __shfl_xor(sum, 8);
            const float r  = 1.0f / sum;
            const int  il  = w * 16 + g * 4 + reg;
            sh[AL_OFF + il * AL_S +  0 + c] = f2bf(p0 * r);
            sh[AL_OFF + il * AL_S + 16 + c] = f2bf(p1 * r);
            sh[AL_OFF + il * AL_S + 32 + c] = f2bf(p2 * r);
            sh[AL_OFF + il * AL_S + 48 + c] = f2bf(p3 * r);
        }
        // no barrier: PV reads only THIS wave's alpha rows (within-wave LDS order)

        // ---- PV: out rows of this wave's i-tile, 8 n-tiles ----
        const int il = w * 16 + c;
        const u32x4 pa0 = *(const u32x4*)(const void*)(sh + AL_OFF + il * AL_S + goff);
        const u32x4 pa1 = *(const u32x4*)(const void*)(sh + AL_OFF + il * AL_S + 32 + goff);
        #pragma unroll
        for (int nt = 0; nt < 8; ++nt) {
            const u32x4 v0 = *(const u32x4*)(const void*)(sh + HT_OFF + (nt * 16 + c) * HT_S + goff);
            const u32x4 v1 = *(const u32x4*)(const void*)(sh + HT_OFF + (nt * 16 + c) * HT_S + 32 + goff);
            f32x4 accp = (f32x4){0.f, 0.f, 0.f, 0.f};
            accp = mfma16(pa0, v0, accp);
            accp = mfma16(pa1, v1, accp);
            #pragma unroll
            for (int reg = 0; reg < 4; ++reg) {
                const int ig = w * 16 + g * 4 + reg;
                if (ig < NN)
                    out[((size_t)b * NN + ig) * DD + nt * 16 + c] = accp[reg];
            }
        }
    } else {
        // ===== attr GEMM via MFMA, 32-way k-split, 2 chunks batched-load -> ws =====
        // blk in [0,512): mg = blk>>5 (16 rows), ks = blk&31 (chunks ks and ks+32)
        const int mg = blk >> 5;
        const int ks = blk & 31;
        const int m0 = mg * 16;
        const int wd = w * 32;
        const float* Arow = A_attr + (size_t)(m0 + c) * MAXA;

        // ---- chunk 0: s0 = ks <= 31 -> k <= 1023, never needs guards ----
        const int k0 = ks * 32;
        const float4 aL0 = *(const float4*)(Arow + k0 + goff);
        const float4 aH0 = *(const float4*)(Arow + k0 + goff + 4);
        float ev0[2][8];
        #pragma unroll
        for (int ntl = 0; ntl < 2; ++ntl) {
            const int col = wd + ntl * 16 + c;
            #pragma unroll
            for (int p = 0; p < 8; ++p)
                ev0[ntl][p] = attr_emb[(size_t)(k0 + goff + p) * DD + col];
        }
        // ---- chunk 1: s1 = ks+32 in [32,63]; skip s1==63; guard tail of s1==62 ----
        const int  s1   = ks + 32;
        const bool has1 = (s1 < 63);                  // wave-uniform
        const int  k1   = s1 * 32;
        float4 aL1 = make_float4(0.f, 0.f, 0.f, 0.f);
        float4 aH1 = make_float4(0.f, 0.f, 0.f, 0.f);
        float ev1[2][8];
        #pragma unroll
        for (int ntl = 0; ntl < 2; ++ntl)
            #pragma unroll
            for (int p = 0; p < 8; ++p) ev1[ntl][p] = 0.f;
        if (has1) {
            if (k1 + goff + 3 < MAXA) aL1 = *(const float4*)(Arow + k1 + goff);
            if (k1 + goff + 7 < MAXA) aH1 = *(const float4*)(Arow + k1 + goff + 4);
            #pragma unroll
            for (int ntl = 0; ntl < 2; ++ntl) {
                const int col = wd + ntl * 16 + c;
                #pragma unroll
                for (int p = 0; p < 8; ++p) {
                    const int kr = k1 + goff + p;
                    ev1[ntl][p] = (kr < MAXA) ? attr_emb[(size_t)kr * DD + col] : 0.f;
                }
            }
        }
        // ---- pack + MFMA both chunks (loads all issued above) ----
        f32x4 acc2[2];
        acc2[0] = (f32x4){0.f, 0.f, 0.f, 0.f};
        acc2[1] = (f32x4){0.f, 0.f, 0.f, 0.f};
        {
            u32x4 af;
            af[0] = pack2(aL0.x, aL0.y); af[1] = pack2(aL0.z, aL0.w);
            af[2] = pack2(aH0.x, aH0.y); af[3] = pack2(aH0.z, aH0.w);
            #pragma unroll
            for (int ntl = 0; ntl < 2; ++ntl) {
                u32x4 bf_;
                bf_[0] = pack2(ev0[ntl][0], ev0[ntl][1]); bf_[1] = pack2(ev0[ntl][2], ev0[ntl][3]);
                bf_[2] = pack2(ev0[ntl][4], ev0[ntl][5]); bf_[3] = pack2(ev0[ntl][6], ev0[ntl][7]);
                acc2[ntl] = mfma16(af, bf_, acc2[ntl]);
            }
        }
        if (has1) {
            u32x4 af;
            af[0] = pack2(aL1.x, aL1.y); af[1] = pack2(aL1.z, aL1.w);
            af[2] = pack2(aH1.x, aH1.y); af[3] = pack2(aH1.z, aH1.w);
            #pragma unroll
            for (int ntl = 0; ntl < 2; ++ntl) {
                u32x4 bf_;
                bf_[0] = pack2(ev1[ntl][0], ev1[ntl][1]); bf_[1] = pack2(ev1[ntl][2], ev1[ntl][3]);
                bf_[2] = pack2(ev1[ntl][4], ev1[ntl][5]); bf_[3] = pack2(ev1[ntl][6], ev1[ntl][7]);
                acc2[ntl] = mfma16(af, bf_, acc2[ntl]);
            }
        }
        // store partial tile (deterministic slot, fully overwritten every call)
        float* pt = ws + (size_t)blk * (16 * DD);
        #pragma unroll
        for (int ntl = 0; ntl < 2; ++ntl)
            #pragma unroll
            for (int reg = 0; reg < 4; ++reg)
                pt[(g * 4 + reg) * DD + wd + ntl * 16 + c] = acc2[ntl][reg];
    }
}

// sum the 32 k-split partials per output element (float4-vectorized)
__global__ __launch_bounds__(256) void attr_reduce_kernel(
    const float* __restrict__ ws, float* __restrict__ attr_out)
{
    const int idx = blockIdx.x * 256 + threadIdx.x;   // 0..8191
    const int m  = idx >> 5;           // 0..255
    const int d4 = idx & 31;           // float4 index within row
    const int mg = m >> 4;
    const int r  = m & 15;
    const float4* base = (const float4*)ws + (size_t)(mg * 32) * 512 + r * 32 + d4;
    float4 v = make_float4(0.f, 0.f, 0.f, 0.f);
    #pragma unroll
    for (int ks = 0; ks < 32; ++ks) {
        const float4 t = base[(size_t)ks * 512];
        v.x += t.x; v.y += t.y; v.z += t.z; v.w += t.w;
    }
    ((float4*)attr_out)[(size_t)m * 32 + d4] = v;
}

extern "C" void kernel_launch(void* const* d_in, const int* in_sizes, int n_in,
                              void* d_out, int out_size, void* d_ws, size_t ws_size,
                              hipStream_t stream) {
    const int*   inputs    = (const int*)  d_in[0];
    const int*   adj       = (const int*)  d_in[1];
    // d_in[2] = mask_item (unused by the reference)
    const float* A_attr    = (const float*)d_in[3];
    const float* embedding = (const float*)d_in[4];
    const float* attr_emb  = (const float*)d_in[5];
    const float* a0        = (const float*)d_in[6];
    const float* a1        = (const float*)d_in[7];
    const float* a2        = (const float*)d_in[8];
    const float* a3        = (const float*)d_in[9];

    float* out      = (float*)d_out;                 // [B,N,D] flat
    float* attr_out = out + (size_t)BB * NN * DD;    // [B,D] flat, concatenated
    float* ws       = (float*)d_ws;                  // 512*2048 f32 = 4 MB

    sg_fused_kernel<<<NATTR + BB, 256, 0, stream>>>(inputs, adj, A_attr, embedding,
                                                    attr_emb, a0, a1, a2, a3,
                                                    out, ws);
    attr_reduce_kernel<<<32, 256, 0, stream>>>(ws, attr_out);
}

// Round 11
// 21.731 us; speedup vs baseline: 1.1530x; 1.1530x over previous
//
#include <hip/hip_runtime.h>
#include <math.h>

#define BB 256
#define NN 50
#define DD 128
#define MAXA 2000
#define NEGV -9e15f
#define NATTR 256                      // 16 m-groups x 16 k-splits

// u16 strides; 16B-granule strides are ODD (17/9/5) -> bank-quads balanced, NO XOR
#define H_S   136                      // H  [64 i][128 d + pad]
#define HT_S  72                       // HT [128 d][64 i + pad]
#define AL_S  72                       // alpha [64 i][64 j + pad]

#define H_OFF   0
#define HT_OFF  (64 * H_S)             // 8704
#define AL_OFF  (HT_OFF + 128 * HT_S)  // 17920
#define ADJ_OFF (AL_OFF + 64 * AL_S)   // 22528
#define LDS_US  (ADJ_OFF + 64 * 64)    // 26624 u16 = 53248 B

typedef __attribute__((ext_vector_type(8))) short        s8b;
typedef __attribute__((ext_vector_type(4))) float        f32x4;
typedef __attribute__((ext_vector_type(4))) unsigned int u32x4;

// HW packed f32x2 -> bf16x2 (RNE), 1 VALU op (no builtin on gfx950 -> asm)
static __device__ __forceinline__ unsigned int pack2(float lo, float hi) {
    unsigned int r;
    asm("v_cvt_pk_bf16_f32 %0, %1, %2" : "=v"(r) : "v"(lo), "v"(hi));
    return r;
}
static __device__ __forceinline__ float bf2f(unsigned int s) {
    return __uint_as_float(s << 16);
}
static __device__ __forceinline__ f32x4 mfma16(u32x4 a, u32x4 b, f32x4 c) {
    return __builtin_amdgcn_mfma_f32_16x16x32_bf16(
        __builtin_bit_cast(s8b, a), __builtin_bit_cast(s8b, b), c, 0, 0, 0);
}

__global__ __launch_bounds__(256) void sg_fused_kernel(
    const int* __restrict__ inputs,      // [B,N]
    const int* __restrict__ adj,         // [B,N,N]
    const float* __restrict__ A_attr,    // [B,MAXA]
    const float* __restrict__ embedding, // [N_NODE,D]
    const float* __restrict__ attr_emb,  // [MAXA,D]
    const float* __restrict__ a0,
    const float* __restrict__ a1,
    const float* __restrict__ a2,
    const float* __restrict__ a3,
    float* __restrict__ out,             // [B,N,D]
    float* __restrict__ ws)              // [256][16][128] f32 attr partials
{
    __shared__ __align__(16) unsigned short sh[LDS_US];
    const int blk  = blockIdx.x;
    const int tid  = threadIdx.x;
    const int w    = tid >> 6;
    const int lane = tid & 63;
    const int g    = lane >> 4;
    const int c    = lane & 15;
    const int goff = g * 8;

    if (blk < BB) {
        // ================= GAT: one block per batch, wave w = i-tile w =================
        const int b = blk;

        // ---- issue embedding gathers EARLY (latency hides under adj staging) ----
        const int  i_   = lane;
        const bool live = (i_ < NN);
        int node = 0;
        if (live) node = inputs[b * NN + i_];
        float4 gv[8];
        #pragma unroll
        for (int n = 0; n < 8; ++n) {
            gv[n] = make_float4(0.f, 0.f, 0.f, 0.f);
            if (live) gv[n] = *(const float4*)(embedding + (size_t)node * DD + (w * 8 + n) * 4);
        }
        // ---- adj -> LDS (zero-padded to 64x64) ----
        for (int idx = tid; idx < 4096; idx += 256) {
            const int i = idx >> 6, j = idx & 63;
            int a = 0;
            if (i < NN && j < NN) a = adj[(size_t)b * (NN * NN) + i * NN + j];
            sh[ADJ_OFF + idx] = (unsigned short)a;
        }
        // ---- convert (cvt_pk) + store H (row-major) and HT (transposed) ----
        #pragma unroll
        for (int n = 0; n < 8; ++n) {
            const int d4 = w * 8 + n;
            const unsigned int pk01 = pack2(gv[n].x, gv[n].y);
            const unsigned int pk23 = pack2(gv[n].z, gv[n].w);
            *(uint2*)(sh + H_OFF + i_ * H_S + d4 * 4) = make_uint2(pk01, pk23);
            sh[HT_OFF + (d4 * 4 + 0) * HT_S + i_] = (unsigned short)pk01;
            sh[HT_OFF + (d4 * 4 + 1) * HT_S + i_] = (unsigned short)(pk01 >> 16);
            sh[HT_OFF + (d4 * 4 + 2) * HT_S + i_] = (unsigned short)pk23;
            sh[HT_OFF + (d4 * 4 + 3) * HT_S + i_] = (unsigned short)(pk23 >> 16);
        }
        __syncthreads();

        // ---- hoist this wave's A-side row fragments, unpacked f32 + abs ----
        u32x4 hA[4];
        float hf[4][8], hb[4][8];
        #pragma unroll
        for (int dt = 0; dt < 4; ++dt) {
            hA[dt] = *(const u32x4*)(const void*)(sh + H_OFF + (w * 16 + c) * H_S + dt * 32 + goff);
            #pragma unroll
            for (int p = 0; p < 4; ++p) {
                const unsigned int hp = hA[dt][p];
                hf[dt][2 * p]     = bf2f(hp & 0xffffu);
                hf[dt][2 * p + 1] = bf2f(hp >> 16);
                hb[dt][2 * p]     = fabsf(hf[dt][2 * p]);
                hb[dt][2 * p + 1] = fabsf(hf[dt][2 * p + 1]);
            }
        }
        // ---- scores: e_k = (H⊙0.6a_k)·H^T + (|H|⊙0.4a_k)·|H|^T ----
        f32x4 accS[4][4];                 // [jt][k]
        #pragma unroll
        for (int jt = 0; jt < 4; ++jt)
            #pragma unroll
            for (int k = 0; k < 4; ++k) accS[jt][k] = (f32x4){0.f, 0.f, 0.f, 0.f};

        #pragma unroll
        for (int pass = 0; pass < 2; ++pass) {
            u32x4 Uf[4][2], Vf[4][2];
            #pragma unroll
            for (int kk = 0; kk < 2; ++kk) {
                const int k = pass * 2 + kk;
                const float* ap = (k == 0) ? a0 : (k == 1) ? a1 : (k == 2) ? a2 : a3;
                #pragma unroll
                for (int dt = 0; dt < 4; ++dt) {
                    const float4 aL = *(const float4*)(ap + dt * 32 + goff);
                    const float4 aH = *(const float4*)(ap + dt * 32 + goff + 4);
                    const float a8[8] = {aL.x, aL.y, aL.z, aL.w, aH.x, aH.y, aH.z, aH.w};
                    u32x4 U, V;
                    #pragma unroll
                    for (int p = 0; p < 4; ++p) {
                        U[p] = pack2(0.6f * a8[2 * p] * hf[dt][2 * p],
                                     0.6f * a8[2 * p + 1] * hf[dt][2 * p + 1]);
                        V[p] = pack2(0.4f * a8[2 * p] * hb[dt][2 * p],
                                     0.4f * a8[2 * p + 1] * hb[dt][2 * p + 1]);
                    }
                    Uf[dt][kk] = U; Vf[dt][kk] = V;
                }
            }
            #pragma unroll
            for (int jt = 0; jt < 4; ++jt) {
                #pragma unroll
                for (int dt = 0; dt < 4; ++dt) {
                    const u32x4 hB = *(const u32x4*)(const void*)(sh + H_OFF + (jt * 16 + c) * H_S + dt * 32 + goff);
                    u32x4 hBa;
                    #pragma unroll
                    for (int p = 0; p < 4; ++p) hBa[p] = hB[p] & 0x7fff7fffu;
                    accS[jt][pass * 2 + 0] = mfma16(Uf[dt][0], hB,  accS[jt][pass * 2 + 0]);
                    accS[jt][pass * 2 + 0] = mfma16(Vf[dt][0], hBa, accS[jt][pass * 2 + 0]);
                    accS[jt][pass * 2 + 1] = mfma16(Uf[dt][1], hB,  accS[jt][pass * 2 + 1]);
                    accS[jt][pass * 2 + 1] = mfma16(Vf[dt][1], hBa, accS[jt][pass * 2 + 1]);
                }
            }
        }

        // ---- adj select + in-register softmax (C/D: col=c, row=g*4+reg) ----
        float s_[4][4];
        #pragma unroll
        for (int jt = 0; jt < 4; ++jt) {
            #pragma unroll
            for (int reg = 0; reg < 4; ++reg) {
                const int il = w * 16 + g * 4 + reg;
                const int j  = jt * 16 + c;
                const int a  = (int)sh[ADJ_OFF + il * 64 + j];
                float sv = (a == 1) ? accS[jt][0][reg] : (a == 2) ? accS[jt][1][reg]
                         : (a == 3) ? accS[jt][2][reg] : (a == 4) ? accS[jt][3][reg] : NEGV;
                if (j >= NN) sv = -INFINITY;
                s_[jt][reg] = sv;
            }
        }
        #pragma unroll
        for (int reg = 0; reg < 4; ++reg) {
            float m = fmaxf(fmaxf(s_[0][reg], s_[1][reg]), fmaxf(s_[2][reg], s_[3][reg]));
            m = fmaxf(m, __shfl_xor(m, 1));
            m = fmaxf(m, __shfl_xor(m, 2));
            m = fmaxf(m, __shfl_xor(m, 4));
            m = fmaxf(m, __shfl_xor(m, 8));
            const float p0 = __expf(s_[0][reg] - m);
            const float p1 = __expf(s_[1][reg] - m);
            const float p2 = __expf(s_[2][reg] - m);
            const float p3 = __expf(s_[3][reg] - m);
            float sum = (p0 + p1) + (p2 + p3);
            sum += __shfl_xor(sum, 1);
            sum += __shfl_xor(sum, 2);
            sum += __shfl_xor(sum, 4);
            sum += __shfl_xor(sum, 8);
            const float r  = 1.0f / sum;
            const int  il  = w * 16 + g * 4 + reg;
            sh[AL_OFF + il * AL_S +  0 + c] = (unsigned short)pack2(p0 * r, p0 * r);
            sh[AL_OFF + il * AL_S + 16 + c] = (unsigned short)pack2(p1 * r, p1 * r);
            sh[AL_OFF + il * AL_S + 32 + c] = (unsigned short)pack2(p2 * r, p2 * r);
            sh[AL_OFF + il * AL_S + 48 + c] = (unsigned short)pack2(p3 * r, p3 * r);
        }
        // no barrier: PV reads only THIS wave's alpha rows (within-wave LDS order)

        // ---- PV: out rows of this wave's i-tile, 8 n-tiles ----
        const int il = w * 16 + c;
        const u32x4 pa0 = *(const u32x4*)(const void*)(sh + AL_OFF + il * AL_S + goff);
        const u32x4 pa1 = *(const u32x4*)(const void*)(sh + AL_OFF + il * AL_S + 32 + goff);
        #pragma unroll
        for (int nt = 0; nt < 8; ++nt) {
            const u32x4 v0 = *(const u32x4*)(const void*)(sh + HT_OFF + (nt * 16 + c) * HT_S + goff);
            const u32x4 v1 = *(const u32x4*)(const void*)(sh + HT_OFF + (nt * 16 + c) * HT_S + 32 + goff);
            f32x4 accp = (f32x4){0.f, 0.f, 0.f, 0.f};
            accp = mfma16(pa0, v0, accp);
            accp = mfma16(pa1, v1, accp);
            #pragma unroll
            for (int reg = 0; reg < 4; ++reg) {
                const int ig = w * 16 + g * 4 + reg;
                if (ig < NN)
                    out[((size_t)b * NN + ig) * DD + nt * 16 + c] = accp[reg];
            }
        }
    } else {
        // ===== attr GEMM via MFMA, 16-way k-split, 4 chunks batched -> ws =====
        // ablk in [0,256): mg = ablk>>4 (16 rows), ks = ablk&15 (chunks ks+16q)
        const int ablk = blk - BB;
        const int mg = ablk >> 4;
        const int ks = ablk & 15;
        const int m0 = mg * 16;
        const int wd = w * 32;
        const float* Arow = A_attr + (size_t)(m0 + c) * MAXA;

        f32x4 acc2[2];
        acc2[0] = (f32x4){0.f, 0.f, 0.f, 0.f};
        acc2[1] = (f32x4){0.f, 0.f, 0.f, 0.f};

        auto do_chunk = [&](int k0, bool guard) {
            float4 aL = make_float4(0.f, 0.f, 0.f, 0.f);
            float4 aH = make_float4(0.f, 0.f, 0.f, 0.f);
            if (!guard || k0 + goff + 3 < MAXA) aL = *(const float4*)(Arow + k0 + goff);
            if (!guard || k0 + goff + 7 < MAXA) aH = *(const float4*)(Arow + k0 + goff + 4);
            u32x4 af;
            af[0] = pack2(aL.x, aL.y); af[1] = pack2(aL.z, aL.w);
            af[2] = pack2(aH.x, aH.y); af[3] = pack2(aH.z, aH.w);
            #pragma unroll
            for (int ntl = 0; ntl < 2; ++ntl) {
                const int col = wd + ntl * 16 + c;
                float ev[8];
                #pragma unroll
                for (int p = 0; p < 8; ++p) {
                    const int kr = k0 + goff + p;
                    ev[p] = (!guard || kr < MAXA) ? attr_emb[(size_t)kr * DD + col] : 0.f;
                }
                u32x4 bf_;
                bf_[0] = pack2(ev[0], ev[1]); bf_[1] = pack2(ev[2], ev[3]);
                bf_[2] = pack2(ev[4], ev[5]); bf_[3] = pack2(ev[6], ev[7]);
                acc2[ntl] = mfma16(af, bf_, acc2[ntl]);
            }
        };
        // chunks ks, ks+16, ks+32: k <= 46*32+31 < 1536+32 -> always in bounds
        #pragma unroll
        for (int q = 0; q < 3; ++q) do_chunk((ks + q * 16) * 32, false);
        // chunk ks+48 in [48,63]: 63 doesn't exist; 62 has a partial tail
        if (ks + 48 < 63) do_chunk((ks + 48) * 32, (ks + 48) == 62);

        // store partial tile (deterministic slot, fully overwritten every call)
        float* pt = ws + (size_t)ablk * (16 * DD);
        #pragma unroll
        for (int ntl = 0; ntl < 2; ++ntl)
            #pragma unroll
            for (int reg = 0; reg < 4; ++reg)
                pt[(g * 4 + reg) * DD + wd + ntl * 16 + c] = acc2[ntl][reg];
    }
}

// sum the 16 k-split partials per output element: attr_out[m][d]
__global__ __launch_bounds__(256) void attr_reduce_kernel(
    const float* __restrict__ ws, float* __restrict__ attr_out)
{
    const int idx = blockIdx.x * 256 + threadIdx.x;   // 0..32767
    const int m  = idx >> 7;           // 0..255
    const int d  = idx & 127;
    const int mg = m >> 4;
    const int r  = m & 15;
    const size_t base = (size_t)mg * 16 * (16 * DD) + r * DD + d;
    float v = 0.f;
    #pragma unroll
    for (int ks = 0; ks < 16; ++ks)
        v += ws[base + (size_t)ks * (16 * DD)];
    attr_out[(size_t)m * DD + d] = v;
}

extern "C" void kernel_launch(void* const* d_in, const int* in_sizes, int n_in,
                              void* d_out, int out_size, void* d_ws, size_t ws_size,
                              hipStream_t stream) {
    const int*   inputs    = (const int*)  d_in[0];
    const int*   adj       = (const int*)  d_in[1];
    // d_in[2] = mask_item (unused by the reference)
    const float* A_attr    = (const float*)d_in[3];
    const float* embedding = (const float*)d_in[4];
    const float* attr_emb  = (const float*)d_in[5];
    const float* a0        = (const float*)d_in[6];
    const float* a1        = (const float*)d_in[7];
    const float* a2        = (const float*)d_in[8];
    const float* a3        = (const float*)d_in[9];

    float* out      = (float*)d_out;                 // [B,N,D] flat
    float* attr_out = out + (size_t)BB * NN * DD;    // [B,D] flat, concatenated
    float* ws       = (float*)d_ws;                  // 256*2048 f32 = 2 MB

    sg_fused_kernel<<<BB + NATTR, 256, 0, stream>>>(inputs, adj, A_attr, embedding,
                                                    attr_emb, a0, a1, a2, a3,
                                                    out, ws);
    attr_reduce_kernel<<<128, 256, 0, stream>>>(ws, attr_out);
}